// Round 6
// baseline (403.270 us; speedup 1.0000x reference)
//
#include <hip/hip_runtime.h>
#include <stdint.h>

#define B_ 16
#define C_ 64
#define H_ 112
#define W_ 112
#define N_ 256

typedef __attribute__((ext_vector_type(8))) short short8;
typedef __attribute__((ext_vector_type(4))) float floatx4;

typedef __attribute__((address_space(1))) const uint32_t gas_u32;
typedef __attribute__((address_space(3))) uint32_t las_u32;

__device__ __forceinline__ uint32_t f2bf_bits(float f) {
  uint32_t u = __float_as_uint(f);
  return (u + 0x7fffu + ((u >> 16) & 1u)) >> 16;  // RNE f32 -> bf16 bits
}

// NCHW f32 -> [b][i][j][c] packed uint32: low16 = bf16(x), high16 = bf16(x^2)
__global__ __launch_bounds__(256) void xform_x(const float* __restrict__ x,
                                               uint32_t* __restrict__ xq) {
  __shared__ float ls[64][113];  // +1 pad: odd stride -> conflict-free transpose read
  int bi = blockIdx.x;
  int b = bi / H_, i = bi % H_;
  const float* xbase = x + ((size_t)b * C_) * (H_ * W_) + (size_t)i * W_;
  for (int idx = threadIdx.x; idx < C_ * 28; idx += 256) {  // 28 float4 per row
    int c = idx / 28, j4 = (idx - c * 28) * 4;
    float4 v = *(const float4*)(xbase + (size_t)c * (H_ * W_) + j4);
    ls[c][j4] = v.x;
    ls[c][j4 + 1] = v.y;
    ls[c][j4 + 2] = v.z;
    ls[c][j4 + 3] = v.w;
  }
  __syncthreads();
  uint32_t* orow = xq + ((size_t)(b * H_ + i)) * (W_ * C_);
  for (int idx = threadIdx.x; idx < W_ * 16; idx += 256) {  // 16 uint4 per site
    int j = idx >> 4, c4 = (idx & 15) * 4;
    float a0 = ls[c4][j], a1 = ls[c4 + 1][j], a2 = ls[c4 + 2][j], a3 = ls[c4 + 3][j];
    uint4 o;
    o.x = f2bf_bits(a0) | (f2bf_bits(a0 * a0) << 16);
    o.y = f2bf_bits(a1) | (f2bf_bits(a1 * a1) << 16);
    o.z = f2bf_bits(a2) | (f2bf_bits(a2 * a2) << 16);
    o.w = f2bf_bits(a3) | (f2bf_bits(a3 * a3) << 16);
    *(uint4*)(orow + j * 64 + c4) = o;
  }
}

// Weights -> Wg[slice = cg*18+tap*2+kk][256n x 16dw], XOR-swizzled (r4-verified):
//   site sn = n>>1 (128B), cpos = (n&1)*4 + (d>>2), stored at cpos^(sn&7).
//   low16 = bf16(2|w|t), high16 = bf16(-|w|). Staging is a LINEAR 16KB copy.
// Also computes cN[n] = sum |w| t^2 (fused, one block per n).
__global__ __launch_bounds__(64) void prep_wc(const float* __restrict__ sw,
                                              const float* __restrict__ tp,
                                              uint32_t* __restrict__ Wg,
                                              float* __restrict__ cN) {
  int n = blockIdx.x, c = threadIdx.x;  // c = 0..63
  int cg = c >> 5, kk = (c >> 4) & 1, ci = c & 15;
  const float* swp = sw + (size_t)(n * C_ + c) * 9;
  const float* tpp = tp + (size_t)(n * C_ + c) * 9;
  int sn = n >> 1;
  int cpos = ((n & 1) << 2) | (ci >> 2);
  int phys = sn * 32 + ((cpos ^ (sn & 7)) << 2) + (ci & 3);
  float s = 0.f;
#pragma unroll
  for (int tap = 0; tap < 9; ++tap) {
    float w = fabsf(swp[tap]);
    float t = tpp[tap];
    s += w * t * t;
    uint32_t v = f2bf_bits(2.0f * w * t) | (f2bf_bits(-w) << 16);
    Wg[(size_t)(cg * 18 + tap * 2 + kk) * 4096 + phys] = v;
  }
#pragma unroll
  for (int off = 32; off > 0; off >>= 1) s += __shfl_down(s, off);
  if (c == 0) cN[n] = s;
}

// r6: identical geometry/layouts/ring to r5; ONLY the window schedule changes.
// r5 post-mortem (T-sink): VGPR_Count==128 (the (512,2) cap) + r5==r4 perf =>
// the scheduler sank the prefetch ds_reads back to their uses to shorten live
// ranges, so every window exposed a full LDS round-trip before its MFMAs.
// Fix: sched_barrier(0) fences pin {loadf(s+1)} BEFORE {domfma(s)}, and a
// second s_barrier after the MFMA cluster (m201 dual-barrier) keeps the 8
// waves in lockstep so skew cannot compound.
// Ring-4 audit (unchanged): dma(s+2) issues window s; slot (s+2)&3 was last
// LDS-read in window s-3 and consumed in s-2, >=2 barriers earlier. vmcnt(2)
// at window s's rendezvous => dma(s+1) landed (4 outstanding: 2+2).
__global__ __launch_bounds__(512, 2) void sim_main(const uint32_t* __restrict__ xq,
                                                   const uint32_t* __restrict__ Wg,
                                                   const float* __restrict__ cN,
                                                   float* __restrict__ out) {
  extern __shared__ uint32_t smem[];
  uint32_t* xs = smem;          // [cg(2)][324 sites][32 dw] = 20736 dw (82944B)
  uint32_t* ws = smem + 20736;  // ring 4 x 4096 dw (65536B)

  int bx = blockIdx.x;
  int b = bx / 49;
  int rem = bx - b * 49;
  int rt = rem / 7, ct = rem - rt * 7;
  int r0 = rt * 16, c0 = ct * 16;
  int tid = threadIdx.x;
  int lane = tid & 63, wv = tid >> 6;
  int wn = wv & 1, wp = wv >> 1;  // wn: which 128-n half, wp: which 4-row group
  int l15 = lane & 15, l4 = lane >> 4;

  floatx4 acc[8][4];  // [nt][pt]; D row = n (l4*4+reg), D col = pixel (l15)
#pragma unroll
  for (int a = 0; a < 8; ++a)
#pragma unroll
    for (int p = 0; p < 4; ++p) acc[a][p] = (floatx4){0.f, 0.f, 0.f, 0.f};

  const uint32_t* xim = xq + (size_t)b * (H_ * W_ * C_);

  // A-frag base: swizzle term is nt-invariant (sn&7 = (l15>>1)&7, n&1 = l15&1)
  int afb = wn * 2048 + (l15 >> 1) * 32 +
            (((((l15 & 1) << 2) | l4) ^ ((l15 >> 1) & 7)) << 2);

  // stage 18x18 halo sites, 32 ch (128B) each, chunk ch at slot ch^(s&7)
  auto stage_xs = [&](int cg) {
    for (int idx = tid; idx < 324 * 8; idx += 512) {
      int s = idx >> 3, ch = idx & 7;
      int row = s / 18, col = s - row * 18;
      int gi = r0 - 1 + row, gj = c0 - 1 + col;
      uint4 v = make_uint4(0u, 0u, 0u, 0u);
      if ((unsigned)gi < (unsigned)H_ && (unsigned)gj < (unsigned)W_)
        v = *(const uint4*)(xim + ((size_t)(gi * W_ + gj)) * C_ + cg * 32 + ch * 4);
      *(uint4*)(&xs[cg * 10368 + s * 32 + ((ch ^ (s & 7)) << 2)]) = v;
    }
  };
  // stage 16KB weight slice s -> ring slot s&3 (linear; lds dest wave-uniform)
  auto stage_w = [&](int s) {
#pragma unroll
    for (int k = 0; k < 2; ++k) {
      const uint32_t* g = Wg + (size_t)s * 4096 + k * 2048 + wv * 256 + lane * 4;
      uint32_t* l = &ws[(s & 3) * 4096 + k * 2048 + wv * 256];
      __builtin_amdgcn_global_load_lds((gas_u32*)g, (las_u32*)l, 16, 0, 0);
    }
  };

  auto loadf = [&](int s, short8* af, short8* bf) {
    const uint32_t* wsb = ws + (s & 3) * 4096 + afb;
#pragma unroll
    for (int nt = 0; nt < 8; ++nt) af[nt] = *(const short8*)(wsb + nt * 256);
    int t2 = (s < 18) ? s : s - 18;
    int tap = t2 >> 1;
    int dp = tap / 3, dq = tap - dp * 3;
    int chb = ((s & 1) << 2) | l4;  // kk*4 + l4
    const uint32_t* xb = xs + ((s < 18) ? 0 : 10368);
#pragma unroll
    for (int pt = 0; pt < 4; ++pt) {
      int st = (wp * 4 + pt + dp) * 18 + l15 + dq;
      bf[pt] = *(const short8*)(xb + st * 32 + ((chb ^ (st & 7)) << 2));
    }
  };
  auto domfma = [&](short8* af, short8* bf) {
    __builtin_amdgcn_s_setprio(1);
#pragma unroll
    for (int nt = 0; nt < 8; ++nt)
#pragma unroll
      for (int pt = 0; pt < 4; ++pt)
        acc[nt][pt] =
            __builtin_amdgcn_mfma_f32_16x16x32_bf16(af[nt], bf[pt], acc[nt][pt], 0, 0, 0);
    __builtin_amdgcn_s_setprio(0);
  };

  // prologue: xs for BOTH cg, slices 0,1 in flight -> one full drain
  stage_xs(0);
  stage_xs(1);
  stage_w(0);
  stage_w(1);
  __syncthreads();

  short8 afA[8], bfA[4], afB[8], bfB[4];
  loadf(0, afA, bfA);

#pragma unroll 1
  for (int ss = 0; ss < 17; ++ss) {  // windows s = 0..33 (pairs)
    int s = ss * 2;
    // window s: consume A, prefetch B = frags(s+1)
    stage_w(s + 2);
    asm volatile("s_waitcnt vmcnt(2)" ::: "memory");
    __builtin_amdgcn_s_barrier();
    __builtin_amdgcn_sched_barrier(0);
    loadf(s + 1, afB, bfB);
    __builtin_amdgcn_sched_barrier(0);  // loads pinned above the MFMA cluster
    domfma(afA, bfA);
    __builtin_amdgcn_s_barrier();  // dual barrier: lockstep, no cross-window skew
    // window s+1: consume B, prefetch A = frags(s+2)
    stage_w(s + 3);
    asm volatile("s_waitcnt vmcnt(2)" ::: "memory");
    __builtin_amdgcn_s_barrier();
    __builtin_amdgcn_sched_barrier(0);
    loadf(s + 2, afA, bfA);
    __builtin_amdgcn_sched_barrier(0);
    domfma(afB, bfB);
    __builtin_amdgcn_s_barrier();
  }
  // window 34: consume A(34), prefetch B(35); only dma(35) outstanding
  asm volatile("s_waitcnt vmcnt(0)" ::: "memory");
  __builtin_amdgcn_s_barrier();
  __builtin_amdgcn_sched_barrier(0);
  loadf(35, afB, bfB);
  __builtin_amdgcn_sched_barrier(0);
  domfma(afA, bfA);  // s=34
  domfma(afB, bfB);  // s=35 (compiler lgkm-gates on bfB/afB arrival)

  // epilogue: out[b][n][r][col] = acc - const[n]; lanes 0..15 -> consecutive cols
#pragma unroll
  for (int nt = 0; nt < 8; ++nt) {
#pragma unroll
    for (int v = 0; v < 4; ++v) {
      int n = wn * 128 + nt * 16 + l4 * 4 + v;
      float cv = cN[n];
#pragma unroll
      for (int pt = 0; pt < 4; ++pt) {
        int r = r0 + wp * 4 + pt;
        int col = c0 + l15;
        out[(((size_t)b * N_ + n) * H_ + r) * W_ + col] = acc[nt][pt][v] - cv;
      }
    }
  }
}

extern "C" void kernel_launch(void* const* d_in, const int* in_sizes, int n_in,
                              void* d_out, int out_size, void* d_ws, size_t ws_size,
                              hipStream_t stream) {
  const float* x = (const float*)d_in[0];
  const float* sw = (const float*)d_in[1];
  const float* tp = (const float*)d_in[2];
  float* out = (float*)d_out;

  // workspace layout
  const size_t xq_bytes = (size_t)B_ * H_ * W_ * C_ * 4;  // 51,380,224
  const size_t wg_bytes = (size_t)36 * 4096 * 4;          // 589,824
  uint32_t* xq = (uint32_t*)d_ws;
  uint32_t* Wg = (uint32_t*)((char*)d_ws + xq_bytes);
  float* cN = (float*)((char*)d_ws + xq_bytes + wg_bytes);

  const int smem_bytes = (20736 + 4 * 4096) * 4;  // 148,480 B dynamic LDS
  static int smem_set = 0;
  if (!smem_set) {
    hipFuncSetAttribute((const void*)sim_main,
                        hipFuncAttributeMaxDynamicSharedMemorySize, smem_bytes);
    smem_set = 1;
  }

  xform_x<<<dim3(B_ * H_), dim3(256), 0, stream>>>(x, xq);
  prep_wc<<<dim3(N_), dim3(64), 0, stream>>>(sw, tp, Wg, cN);
  sim_main<<<dim3(B_ * 7 * 7), dim3(512), smem_bytes, stream>>>(xq, Wg, cN, out);
}

// Round 8
// 352.601 us; speedup vs baseline: 1.1437x; 1.1437x over previous
//
#include <hip/hip_runtime.h>
#include <stdint.h>

#define B_ 16
#define C_ 64
#define H_ 112
#define W_ 112
#define N_ 256

typedef __attribute__((ext_vector_type(8))) short short8;
typedef __attribute__((ext_vector_type(4))) float floatx4;

typedef __attribute__((address_space(1))) const uint32_t gas_u32;
typedef __attribute__((address_space(3))) uint32_t las_u32;

__device__ __forceinline__ uint32_t f2bf_bits(float f) {
  uint32_t u = __float_as_uint(f);
  return (u + 0x7fffu + ((u >> 16) & 1u)) >> 16;  // RNE f32 -> bf16 bits
}

// NCHW f32 -> [b][i][j][c] packed uint32: low16 = bf16(x), high16 = bf16(x^2)
__global__ __launch_bounds__(256) void xform_x(const float* __restrict__ x,
                                               uint32_t* __restrict__ xq) {
  __shared__ float ls[64][113];  // +1 pad: odd stride -> conflict-free transpose read
  int bi = blockIdx.x;
  int b = bi / H_, i = bi % H_;
  const float* xbase = x + ((size_t)b * C_) * (H_ * W_) + (size_t)i * W_;
  for (int idx = threadIdx.x; idx < C_ * 28; idx += 256) {  // 28 float4 per row
    int c = idx / 28, j4 = (idx - c * 28) * 4;
    float4 v = *(const float4*)(xbase + (size_t)c * (H_ * W_) + j4);
    ls[c][j4] = v.x;
    ls[c][j4 + 1] = v.y;
    ls[c][j4 + 2] = v.z;
    ls[c][j4 + 3] = v.w;
  }
  __syncthreads();
  uint32_t* orow = xq + ((size_t)(b * H_ + i)) * (W_ * C_);
  for (int idx = threadIdx.x; idx < W_ * 16; idx += 256) {  // 16 uint4 per site
    int j = idx >> 4, c4 = (idx & 15) * 4;
    float a0 = ls[c4][j], a1 = ls[c4 + 1][j], a2 = ls[c4 + 2][j], a3 = ls[c4 + 3][j];
    uint4 o;
    o.x = f2bf_bits(a0) | (f2bf_bits(a0 * a0) << 16);
    o.y = f2bf_bits(a1) | (f2bf_bits(a1 * a1) << 16);
    o.z = f2bf_bits(a2) | (f2bf_bits(a2 * a2) << 16);
    o.w = f2bf_bits(a3) | (f2bf_bits(a3 * a3) << 16);
    *(uint4*)(orow + j * 64 + c4) = o;
  }
}

// Weights -> Wg[slice = cg*18+tap*2+kk][256n x 16dw], XOR-swizzled (r4-verified
// ZERO-conflict layout): site sn = n>>1 (128B), cpos = (n&1)*4 + (d>>2), stored
// at cpos^(sn&7). low16 = bf16(2|w|t), high16 = bf16(-|w|). Linear staging.
// Also computes cN[n] = sum |w| t^2 (fused, one block per n).
__global__ __launch_bounds__(64) void prep_wc(const float* __restrict__ sw,
                                              const float* __restrict__ tp,
                                              uint32_t* __restrict__ Wg,
                                              float* __restrict__ cN) {
  int n = blockIdx.x, c = threadIdx.x;  // c = 0..63
  int cg = c >> 5, kk = (c >> 4) & 1, ci = c & 15;
  const float* swp = sw + (size_t)(n * C_ + c) * 9;
  const float* tpp = tp + (size_t)(n * C_ + c) * 9;
  int sn = n >> 1;
  int cpos = ((n & 1) << 2) | (ci >> 2);
  int phys = sn * 32 + ((cpos ^ (sn & 7)) << 2) + (ci & 3);
  float s = 0.f;
#pragma unroll
  for (int tap = 0; tap < 9; ++tap) {
    float w = fabsf(swp[tap]);
    float t = tpp[tap];
    s += w * t * t;
    uint32_t v = f2bf_bits(2.0f * w * t) | (f2bf_bits(-w) << 16);
    Wg[(size_t)(cg * 18 + tap * 2 + kk) * 4096 + phys] = v;
  }
#pragma unroll
  for (int off = 32; off > 0; off >>= 1) s += __shfl_down(s, off);
  if (c == 0) cN[n] = s;
}

// r7 (resubmit; round-7 bench was an infra failure, no measurement): revert to
// the measured-fastest STRUCTURE (r2: 160us, 2 blocks/CU, 4 waves/SIMD) and
// apply only verified fixes. Cross-round evidence: every >=4-waves/SIMD variant
// (160-172us) beat every 2-waves variant (177-188us), and at 2 waves/SIMD three
// different schedules were identical -> TLP, not instruction order, hides
// latency here.
//   - block: 128n (nb half) x 256px, 8 waves, wave = 64n x 4r x 16c, acc 4x4
//   - af from r4's swizzled Wg (measured 0 conflicts; r2 carried 7.2M cycles)
//   - K=64 windows (full tap): 18 barriers/block vs r2's 37; kk-sequential
//     body keeps live arch VGPRs ~56 (r2 level)
//   - ws 2 x 16KB tap-slab double-buffer, DMA issued at window top (r2's
//     discipline), one __syncthreads per window; xs restage at cg boundary
//   - LDS 74,240B -> 2 blocks/CU (dynamic, >64KB static limit)
__global__ __launch_bounds__(512, 4) void sim_main(const uint32_t* __restrict__ xq,
                                                   const uint32_t* __restrict__ Wg,
                                                   const float* __restrict__ cN,
                                                   float* __restrict__ out) {
  extern __shared__ uint32_t smem[];
  uint32_t* xs = smem;          // 324 sites x 32 dw (128B, chunk^(s&7)) = 41472B
  uint32_t* ws = smem + 10368;  // 2 slabs x 4096 dw (16KB tap slab) = 32768B

  int bx = blockIdx.x;
  int nb = bx & 1;
  bx >>= 1;
  int b = bx / 49;
  int rem = bx - b * 49;
  int rt = rem / 7, ct = rem - rt * 7;
  int r0 = rt * 16, c0 = ct * 16;
  int tid = threadIdx.x;
  int lane = tid & 63, wv = tid >> 6;
  int wn = wv & 1, wp = wv >> 1;  // wn: which 64-n half, wp: which 4-row group
  int l15 = lane & 15, l4 = lane >> 4;

  floatx4 acc[4][4];  // [nt][pt]; D row = n (l4*4+reg), D col = pixel (l15)
#pragma unroll
  for (int a = 0; a < 4; ++a)
#pragma unroll
    for (int p = 0; p < 4; ++p) acc[a][p] = (floatx4){0.f, 0.f, 0.f, 0.f};

  const uint32_t* xim = xq + (size_t)b * (H_ * W_ * C_);

  // A-frag base within an 8KB kk-slab (local sites; swizzle key nt-invariant:
  // sn&7 = (l15>>1)&7 because nt*16>>1 is 0 mod 8)
  int afb = wn * 1024 + (l15 >> 1) * 32 +
            (((((l15 & 1) << 2) | l4) ^ ((l15 >> 1) & 7)) << 2);

  // stage 18x18 halo sites, 32 ch (128B) each, chunk ch at slot ch^(s&7)
  auto stage_xs = [&](int cg) {
    for (int idx = tid; idx < 324 * 8; idx += 512) {
      int s = idx >> 3, ch = idx & 7;
      int row = s / 18, col = s - row * 18;
      int gi = r0 - 1 + row, gj = c0 - 1 + col;
      uint4 v = make_uint4(0u, 0u, 0u, 0u);
      if ((unsigned)gi < (unsigned)H_ && (unsigned)gj < (unsigned)W_)
        v = *(const uint4*)(xim + ((size_t)(gi * W_ + gj)) * C_ + cg * 32 + ch * 4);
      *(uint4*)(&xs[s * 32 + ((ch ^ (s & 7)) << 2)]) = v;
    }
  };
  // stage tap-window t (both kk slabs, 16KB for this nb half) -> ws[t&1]
  auto stage_w = [&](int t) {
#pragma unroll
    for (int k = 0; k < 2; ++k) {
      const uint32_t* g =
          Wg + (size_t)(t * 2 + k) * 4096 + nb * 2048 + wv * 256 + lane * 4;
      uint32_t* l = &ws[(t & 1) * 4096 + k * 2048 + wv * 256];
      __builtin_amdgcn_global_load_lds((gas_u32*)g, (las_u32*)l, 16, 0, 0);
    }
  };

  // prologue: xs for cg=0, tap window 0 in flight
  stage_xs(0);
  stage_w(0);
  __syncthreads();

#pragma unroll 1
  for (int t = 0; t < 18; ++t) {  // t = cg*9 + tap
    if (t == 9) {                 // cg boundary: xs(0) readers done (barrier @8)
      stage_xs(1);
      __syncthreads();
    }
    if (t < 17) stage_w(t + 1);  // issue-ahead; lands by this window's barrier
    int tap = (t < 9) ? t : t - 9;
    int dp = tap / 3, dq = tap - dp * 3;
    const uint32_t* slab = ws + (t & 1) * 4096;

#pragma unroll
    for (int kk = 0; kk < 2; ++kk) {  // sequential kk: one frag set live at a time
      const uint32_t* wsb = slab + kk * 2048 + afb;
      int chb = (kk << 2) | l4;
      short8 af[4], bf[4];
#pragma unroll
      for (int nt = 0; nt < 4; ++nt) af[nt] = *(const short8*)(wsb + nt * 256);
#pragma unroll
      for (int pt = 0; pt < 4; ++pt) {
        int st = (wp * 4 + pt + dp) * 18 + l15 + dq;
        bf[pt] = *(const short8*)(&xs[st * 32 + ((chb ^ (st & 7)) << 2)]);
      }
#pragma unroll
      for (int nt = 0; nt < 4; ++nt)
#pragma unroll
        for (int pt = 0; pt < 4; ++pt)
          acc[nt][pt] =
              __builtin_amdgcn_mfma_f32_16x16x32_bf16(af[nt], bf[pt], acc[nt][pt], 0, 0, 0);
    }
    if (t < 17) __syncthreads();  // next slab landed; ws[t&1] safe to overwrite
  }

  // epilogue: out[b][n][r][col] = acc - const[n]; lanes 0..15 -> consecutive cols
#pragma unroll
  for (int nt = 0; nt < 4; ++nt) {
#pragma unroll
    for (int v = 0; v < 4; ++v) {
      int n = nb * 128 + wn * 64 + nt * 16 + l4 * 4 + v;
      float cv = cN[n];
#pragma unroll
      for (int pt = 0; pt < 4; ++pt) {
        int r = r0 + wp * 4 + pt;
        int col = c0 + l15;
        out[(((size_t)b * N_ + n) * H_ + r) * W_ + col] = acc[nt][pt][v] - cv;
      }
    }
  }
}

extern "C" void kernel_launch(void* const* d_in, const int* in_sizes, int n_in,
                              void* d_out, int out_size, void* d_ws, size_t ws_size,
                              hipStream_t stream) {
  const float* x = (const float*)d_in[0];
  const float* sw = (const float*)d_in[1];
  const float* tp = (const float*)d_in[2];
  float* out = (float*)d_out;

  // workspace layout
  const size_t xq_bytes = (size_t)B_ * H_ * W_ * C_ * 4;  // 51,380,224
  const size_t wg_bytes = (size_t)36 * 4096 * 4;          // 589,824
  uint32_t* xq = (uint32_t*)d_ws;
  uint32_t* Wg = (uint32_t*)((char*)d_ws + xq_bytes);
  float* cN = (float*)((char*)d_ws + xq_bytes + wg_bytes);

  const int smem_bytes = (10368 + 2 * 4096) * 4;  // 74,240 B dynamic LDS
  static int smem_set = 0;
  if (!smem_set) {
    hipFuncSetAttribute((const void*)sim_main,
                        hipFuncAttributeMaxDynamicSharedMemorySize, smem_bytes);
    smem_set = 1;
  }

  xform_x<<<dim3(B_ * H_), dim3(256), 0, stream>>>(x, xq);
  prep_wc<<<dim3(N_), dim3(64), 0, stream>>>(sw, tp, Wg, cN);
  sim_main<<<dim3(2 * B_ * 7 * 7), dim3(512), smem_bytes, stream>>>(xq, Wg, cN, out);
}